// Round 19
// baseline (107.776 us; speedup 1.0000x reference)
//
#include <hip/hip_runtime.h>
#include <hip/hip_bf16.h>

// Problem: T=2048, B=32, H=512
//   scores[b,t] = sum_o v[o] * tanh( hb[b,o] + sum_h enc[t,b,h] * W2[o,h] )
//   out[b,0,t]  = softmax_t(scores[b,:])
//
// R19: R17/R18 structure (prep: enc -> bf16 pre-swizzled tile image; main:
// both operands via global_load_lds, main measured ~11us). Prep conversion
// REWRITTEN to stage enc through LDS via global_load_lds (async deep queue,
// no data VGPRs -> latency hidden regardless of allocator), then cvt + 
// dest-linear 16B writes. R17/R18 prep was MLP-2 serialized (VGPR pinned 32).
//
// HARD-WON RULES (R2..R18): WRITE>>2MB on MAIN = spill; gload_lds dest is
// wave-uniform+lane*16B (per-wave dests), SOURCE is per-lane; occupancy not
// the lever; counted vmcnt/setprio negative on 2-phase; trivial mem-kernels
// get VGPR-starved (VGPR=32) -> use gload_lds staging for ILP.

#define TT 2048
#define BB 32
#define HH 512

typedef __attribute__((ext_vector_type(8))) short bf16x8;
typedef __attribute__((ext_vector_type(4))) float f32x4;

static __device__ __forceinline__ unsigned cvt2(float a, float b) {
    union { __hip_bfloat162 h; unsigned u; } cv;
    cv.h = __float22bfloat162_rn(make_float2(a, b));   // v_cvt_pk_bf16_f32
    return cv.u;
}

static __device__ __forceinline__ unsigned short f2bf(float f) {
    unsigned int u = __float_as_uint(f);
    unsigned int r = (u + 0x7FFFu + ((u >> 16) & 1u)) >> 16;  // RNE
    return (unsigned short)r;
}

// tanh(x) = 1 - 2/(1+e^{2x});  inf-safe at both ends.
static __device__ __forceinline__ float fast_tanh(float x) {
    float e = __expf(2.0f * x);
    return 1.0f - 2.0f * __builtin_amdgcn_rcpf(1.0f + e);
}

static __device__ __forceinline__ void gload_lds16(const void* g, void* l) {
    __builtin_amdgcn_global_load_lds(
        (const __attribute__((address_space(1))) unsigned int*)g,
        (__attribute__((address_space(3))) unsigned int*)l, 16, 0, 0);
}

// ======================= PREP (new path) =======================
// blocks [0,4096): enc -> bf16 swizzled tile image, via LDS staging.
//   block = (mtile = bid>>3, ks = bid&7). Stage enc rows t0..t0+128, float
//   cols [ks*64,+64) (256B/row) into Af[128][64] fp32 via gload_lds
//   (8 insts/wave, 4 rows each; per-lane src, wave-uniform dest). Barrier.
//   Then 4 chunks/thread dest-linear: chunk c: r=c>>3, c8=c&7; src floats
//   Af[r][ (c8^(r&7))*8 .. +8 ] -> cvt -> Aimg[mtile*65536 + ks*8192 + c*8].
//   (Mapping identical to R17/R18-verified: offset c8*8 holds src blk c8^(r&7).)
// blocks [4096,5120): W2 pack (R16 layout).
// blocks [5120,5184): hb.
__global__ __launch_bounds__(256, 2) void prep_all_kernel(
    const float* __restrict__ W,
    const float* __restrict__ hidden,
    const float* __restrict__ b_attn,
    const float* __restrict__ enc,
    short* __restrict__ W2p,
    float* __restrict__ hb,
    short* __restrict__ Aimg) {
    __shared__ float Af[128 * 64];    // 32KB staging (conv blocks)
    const int bid = blockIdx.x;
    const int tid = threadIdx.x;
    if (bid < 4096) {
        const int mtile = bid >> 3;
        const int ks = bid & 7;
        const int b = mtile >> 4;
        const int t0 = (mtile & 15) * 128;
        const int wave = tid >> 6;
        const int lane = tid & 63;
        // ---- stage: wave w rows w*32..+32, inst j covers 4 rows (1KB)
        {
            const char* src0 = (const char*)enc +
                ((size_t)t0 * BB + b) * (HH * 4) + ks * 256 + (lane & 15) * 16;
            const int rbase = wave * 32;
#pragma unroll
            for (int j = 0; j < 8; ++j) {
                const int row = rbase + j * 4 + (lane >> 4);
                gload_lds16(src0 + (size_t)row * (BB * HH * 4),
                            &Af[(rbase + j * 4) * 64]);
            }
        }
        __syncthreads();   // drains gload_lds (compiler emits vmcnt(0))
        // ---- convert: 4 consecutive-chunk groups, perfectly coalesced writes
        short* dst = Aimg + (size_t)mtile * 65536 + ks * 8192;
#pragma unroll
        for (int i = 0; i < 4; ++i) {
            const int c = i * 256 + tid;
            const int r = c >> 3, c8 = c & 7;
            const float* s = &Af[r * 64 + ((c8 ^ (r & 7)) * 8)];
            const float4 lo = *reinterpret_cast<const float4*>(s);
            const float4 hi = *reinterpret_cast<const float4*>(s + 4);
            uint4 pk;
            pk.x = cvt2(lo.x, lo.y);
            pk.y = cvt2(lo.z, lo.w);
            pk.z = cvt2(hi.x, hi.y);
            pk.w = cvt2(hi.z, hi.w);
            *reinterpret_cast<uint4*>(dst + (size_t)c * 8) = pk;
        }
    } else if (bid < 5120) {
        int idx = (bid - 4096) * 256 + tid;      // 262144 total
        int nt = idx >> 16;
        int ks = (idx >> 13) & 7;
        int s  = idx & 8191;
        int j  = s >> 6;
        int c  = s & 63;
        int o  = nt * 128 + j;
        int k  = ks * 64 + (c ^ ((j & 7) << 3));
        W2p[idx] = (short)f2bf(W[o * 1024 + 512 + k]);
    } else {
        const int hbid = bid - 5120;
        int b = hbid >> 1;
        int o = ((hbid & 1) << 8) + tid;
        float* hrow = Af;   // reuse staging LDS
        for (int h = tid; h < 512; h += 256) hrow[h] = hidden[b * 512 + h];
        __syncthreads();
        const float4* wr = reinterpret_cast<const float4*>(W + (size_t)o * 1024);
        const float4* hr = reinterpret_cast<const float4*>(hrow);
        float acc = b_attn[o];
#pragma unroll 8
        for (int i = 0; i < 128; ++i) {
            float4 w = wr[i], h4 = hr[i];
            acc += w.x * h4.x + w.y * h4.y + w.z * h4.z + w.w * h4.w;
        }
        hb[b * 512 + o] = acc;
    }
}

// ======================= PREP (fallback path, = R16) =======================
__global__ void prep_kernel(const float* __restrict__ W,
                            const float* __restrict__ hidden,
                            const float* __restrict__ b_attn,
                            short* __restrict__ W2p,
                            float* __restrict__ hb) {
    __shared__ float hrow[512];
    const int bid = blockIdx.x;
    if (bid < 1024) {
        int idx = bid * 256 + threadIdx.x;
        int nt = idx >> 16;
        int ks = (idx >> 13) & 7;
        int s  = idx & 8191;
        int j  = s >> 6;
        int c  = s & 63;
        int o  = nt * 128 + j;
        int k  = ks * 64 + (c ^ ((j & 7) << 3));
        W2p[idx] = (short)f2bf(W[o * 1024 + 512 + k]);
    } else {
        const int hbid = bid - 1024;
        int b = hbid >> 1;
        int o = ((hbid & 1) << 8) + threadIdx.x;
        for (int h = threadIdx.x; h < 512; h += 256) hrow[h] = hidden[b * 512 + h];
        __syncthreads();
        const float4* wr = reinterpret_cast<const float4*>(W + (size_t)o * 1024);
        const float4* hr = reinterpret_cast<const float4*>(hrow);
        float acc = b_attn[o];
#pragma unroll 8
        for (int i = 0; i < 128; ++i) {
            float4 w = wr[i], h4 = hr[i];
            acc += w.x * h4.x + w.y * h4.y + w.z * h4.z + w.w * h4.w;
        }
        hb[b * 512 + o] = acc;
    }
}

// Shared MFMA compute macro (both mains declare identical As/Bs/ids)
#define COMPUTE(BUF)                                                                \
    {                                                                               \
        _Pragma("unroll")                                                           \
        for (int ksub = 0; ksub < 2; ++ksub) {                                      \
            const int kk = ksub * 32 + lq * 8;                                      \
            bf16x8 af[4], bfr[4];                                                   \
            _Pragma("unroll")                                                       \
            for (int mt = 0; mt < 4; ++mt) {                                        \
                const int r = wr * 64 + mt * 16 + lcol;                             \
                af[mt] = *reinterpret_cast<const bf16x8*>(                          \
                    &As[BUF][r * 64 + (kk ^ ((r & 7) << 3))]);                      \
            }                                                                       \
            _Pragma("unroll")                                                       \
            for (int ns = 0; ns < 4; ++ns) {                                        \
                const int j = wc * 64 + ns * 16 + lcol;                             \
                bfr[ns] = *reinterpret_cast<const bf16x8*>(                         \
                    &Bs[BUF][j * 64 + (kk ^ ((j & 7) << 3))]);                      \
            }                                                                       \
            _Pragma("unroll")                                                       \
            for (int mt = 0; mt < 4; ++mt)                                          \
                _Pragma("unroll")                                                   \
                for (int ns = 0; ns < 4; ++ns)                                      \
                    acc[mt][ns] = __builtin_amdgcn_mfma_f32_16x16x32_bf16(          \
                        af[mt], bfr[ns], acc[mt][ns], 0, 0, 0);                     \
        }                                                                           \
    }

// ======================= MAIN (new path): full gload_lds =======================
__global__ __launch_bounds__(256, 2) void attn_main_lds_kernel(
    const short* __restrict__ Aimg, const short* __restrict__ W2p,
    const float* __restrict__ hb, const float* __restrict__ v,
    float* __restrict__ scores_part)
{
    __shared__ short As[2][128 * 64];
    __shared__ short Bs[2][128 * 64];
    __shared__ float s_red[2][128];

    const int tid = threadIdx.x;
    const int bid = blockIdx.x;
    const int w = (bid & 7) * 256 + (bid >> 3);
    const int nt = w & 3;
    const int mtile = w >> 2;
    const int b = mtile >> 4;
    const int t0 = (mtile & 15) * 128;

    const int wave = tid >> 6;
    const int lane = tid & 63;
    const int wr = wave >> 1;
    const int wc = wave & 1;
    const int lcol = lane & 15;
    const int lq = lane >> 4;

    const short* asrc = Aimg + (size_t)mtile * 65536 + wave * 2048 + lane * 8;
    const short* bsrc = W2p + (size_t)nt * 65536 + wave * 2048 + lane * 8;

    f32x4 acc[4][4];
#pragma unroll
    for (int mt = 0; mt < 4; ++mt)
#pragma unroll
        for (int ns = 0; ns < 4; ++ns) acc[mt][ns] = (f32x4){0.f, 0.f, 0.f, 0.f};

#define AB_STAGE(KS, BUF)                                                           \
    {                                                                               \
        const short* a0 = asrc + (KS) * 8192;                                       \
        const short* b0 = bsrc + (KS) * 8192;                                       \
        _Pragma("unroll")                                                           \
        for (int c = 0; c < 4; ++c) {                                               \
            gload_lds16(a0 + c * 512, &As[BUF][wave * 2048 + c * 512]);             \
            gload_lds16(b0 + c * 512, &Bs[BUF][wave * 2048 + c * 512]);             \
        }                                                                           \
    }

    // prologue
    AB_STAGE(0, 0);
    __syncthreads();

#pragma unroll
    for (int s = 0; s < 8; ++s) {
        if (s < 7) AB_STAGE(s + 1, (s & 1) ^ 1);   // issue-early: hides under MFMA
        COMPUTE(s & 1);
        __syncthreads();
    }

    // epilogue: tanh + v-dot, reduce over this block's 128 cols
    float part[4][4];
#pragma unroll
    for (int mt = 0; mt < 4; ++mt)
#pragma unroll
        for (int j = 0; j < 4; ++j) part[mt][j] = 0.0f;

#pragma unroll
    for (int ns = 0; ns < 4; ++ns) {
        const int o = nt * 128 + wc * 64 + ns * 16 + lcol;
        const float hbv = hb[b * 512 + o];
        const float vv = v[o];
#pragma unroll
        for (int mt = 0; mt < 4; ++mt)
#pragma unroll
            for (int j = 0; j < 4; ++j)
                part[mt][j] = fmaf(fast_tanh(acc[mt][ns][j] + hbv), vv, part[mt][j]);
    }

#pragma unroll
    for (int off = 1; off < 16; off <<= 1)
#pragma unroll
        for (int mt = 0; mt < 4; ++mt)
#pragma unroll
            for (int j = 0; j < 4; ++j)
                part[mt][j] += __shfl_xor(part[mt][j], off, 64);

    if (lcol == 0) {
#pragma unroll
        for (int mt = 0; mt < 4; ++mt)
#pragma unroll
            for (int j = 0; j < 4; ++j)
                s_red[wc][wr * 64 + mt * 16 + lq * 4 + j] = part[mt][j];
    }
    __syncthreads();

    if (tid < 128)
        scores_part[((size_t)nt * BB + b) * TT + t0 + tid] =
            s_red[0][tid] + s_red[1][tid];
}

// ======================= MAIN (fallback path, = R16) =======================
__global__ __launch_bounds__(256, 2) void attn_main_kernel(
    const float* __restrict__ enc, const short* __restrict__ W2p,
    const float* __restrict__ hb, const float* __restrict__ v,
    float* __restrict__ scores_part)
{
    __shared__ short As[2][128 * 64];
    __shared__ short Bs[2][128 * 64];
    __shared__ float s_red[2][128];

    const int tid = threadIdx.x;
    const int bid = blockIdx.x;
    const int w = (bid & 7) * 256 + (bid >> 3);
    const int nt = w & 3;
    const int mtile = w >> 2;
    const int b = mtile >> 4;
    const int t0 = (mtile & 15) * 128;

    const int wave = tid >> 6;
    const int lane = tid & 63;
    const int wr = wave >> 1;
    const int wc = wave & 1;
    const int lcol = lane & 15;
    const int lq = lane >> 4;

    const int arow = tid >> 3;
    const int afc = (tid & 7) * 8;
    const float* encbase = enc + ((size_t)(t0 + arow) * BB + b) * HH + afc;
    const short* bsrc = W2p + nt * 65536 + (wave * 4) * 512 + lane * 8;

    f32x4 acc[4][4];
#pragma unroll
    for (int mt = 0; mt < 4; ++mt)
#pragma unroll
        for (int ns = 0; ns < 4; ++ns) acc[mt][ns] = (f32x4){0.f, 0.f, 0.f, 0.f};

    float4 rA0[8], rA1[8];

#define F_A_LOAD(RA, KS)                                                            \
    {                                                                               \
        _Pragma("unroll")                                                           \
        for (int p = 0; p < 4; ++p) {                                               \
            const float* src = encbase + (size_t)p * 32 * BB * HH + (KS) * 64;      \
            RA[p * 2]     = *reinterpret_cast<const float4*>(src);                  \
            RA[p * 2 + 1] = *reinterpret_cast<const float4*>(src + 4);              \
        }                                                                           \
    }

#define F_B_STAGE(KS, BUF)                                                          \
    {                                                                               \
        const short* s0 = bsrc + (KS) * 8192;                                       \
        _Pragma("unroll")                                                           \
        for (int c = 0; c < 4; ++c)                                                 \
            gload_lds16(s0 + c * 512, &Bs[BUF][(wave * 4 + c) * 512]);              \
    }

#define F_A_WRITE(RA, BUF)                                                          \
    {                                                                               \
        _Pragma("unroll")                                                           \
        for (int p = 0; p < 4; ++p) {                                               \
            const int r = p * 32 + arow;                                            \
            uint4 pk;                                                               \
            pk.x = cvt2(RA[p * 2].x, RA[p * 2].y);                                  \
            pk.y = cvt2(RA[p * 2].z, RA[p * 2].w);                                  \
            pk.z = cvt2(RA[p * 2 + 1].x, RA[p * 2 + 1].y);                          \
            pk.w = cvt2(RA[p * 2 + 1].z, RA[p * 2 + 1].w);                          \
            const int cs = afc ^ ((r & 7) << 3);                                    \
            *reinterpret_cast<uint4*>(&As[BUF][r * 64 + cs]) = pk;                  \
        }                                                                           \
    }

    F_A_LOAD(rA0, 0);
    F_A_LOAD(rA1, 1);
    F_B_STAGE(0, 0);
    F_A_WRITE(rA0, 0);
    __syncthreads();

#pragma unroll
    for (int s2 = 0; s2 < 4; ++s2) {
        const int s = s2 * 2;
        if (s + 2 < 8) F_A_LOAD(rA0, s + 2);
        F_B_STAGE(s + 1, 1);
        COMPUTE(0);
        F_A_WRITE(rA1, 1);
        __syncthreads();
        if (s + 3 < 8) F_A_LOAD(rA1, s + 3);
        if (s + 2 < 8) F_B_STAGE(s + 2, 0);
        COMPUTE(1);
        if (s + 2 < 8) {
            F_A_WRITE(rA0, 0);
            __syncthreads();
        }
    }

    float part[4][4];
#pragma unroll
    for (int mt = 0; mt < 4; ++mt)
#pragma unroll
        for (int j = 0; j < 4; ++j) part[mt][j] = 0.0f;

#pragma unroll
    for (int ns = 0; ns < 4; ++ns) {
        const int o = nt * 128 + wc * 64 + ns * 16 + lcol;
        const float hbv = hb[b * 512 + o];
        const float vv = v[o];
#pragma unroll
        for (int mt = 0; mt < 4; ++mt)
#pragma unroll
            for (int j = 0; j < 4; ++j)
                part[mt][j] = fmaf(fast_tanh(acc[mt][ns][j] + hbv), vv, part[mt][j]);
    }

#pragma unroll
    for (int off = 1; off < 16; off <<= 1)
#pragma unroll
        for (int mt = 0; mt < 4; ++mt)
#pragma unroll
            for (int j = 0; j < 4; ++j)
                part[mt][j] += __shfl_xor(part[mt][j], off, 64);

    if (lcol == 0) {
#pragma unroll
        for (int mt = 0; mt < 4; ++mt)
#pragma unroll
            for (int j = 0; j < 4; ++j)
                s_red[wc][wr * 64 + mt * 16 + lq * 4 + j] = part[mt][j];
    }
    __syncthreads();

    if (tid < 128)
        scores_part[((size_t)nt * BB + b) * TT + t0 + tid] =
            s_red[0][tid] + s_red[1][tid];
}

// ======================= softmax =======================
__global__ void softmax_kernel(const float* __restrict__ sp, float* __restrict__ out) {
    __shared__ float wred[4];
    __shared__ float wsum[4];
    const int b = blockIdx.x;
    const int tid = threadIdx.x;   // 256
    float vals[8];
    float mx = -1e30f;
#pragma unroll
    for (int i = 0; i < 8; ++i) {
        const int t = i * 256 + tid;
        const float s = sp[(size_t)b * TT + t] + sp[((size_t)BB + b) * TT + t] +
                        sp[((size_t)2 * BB + b) * TT + t] + sp[((size_t)3 * BB + b) * TT + t];
        vals[i] = s;
        mx = fmaxf(mx, s);
    }
#pragma unroll
    for (int off = 32; off; off >>= 1) mx = fmaxf(mx, __shfl_xor(mx, off, 64));
    if ((tid & 63) == 0) wred[tid >> 6] = mx;
    __syncthreads();
    mx = fmaxf(fmaxf(wred[0], wred[1]), fmaxf(wred[2], wred[3]));
    float s = 0.0f;
#pragma unroll
    for (int i = 0; i < 8; ++i) {
        vals[i] = __expf(vals[i] - mx);
        s += vals[i];
    }
#pragma unroll
    for (int off = 32; off; off >>= 1) s += __shfl_xor(s, off, 64);
    if ((tid & 63) == 0) wsum[tid >> 6] = s;
    __syncthreads();
    s = wsum[0] + wsum[1] + wsum[2] + wsum[3];
    const float inv = 1.0f / s;
#pragma unroll
    for (int i = 0; i < 8; ++i) out[b * TT + i * 256 + tid] = vals[i] * inv;
}

extern "C" void kernel_launch(void* const* d_in, const int* in_sizes, int n_in,
                              void* d_out, int out_size, void* d_ws, size_t ws_size,
                              hipStream_t stream) {
    const float* hidden = (const float*)d_in[0];   // (1,B,H)
    const float* enc    = (const float*)d_in[1];   // (T,B,H)
    const float* W      = (const float*)d_in[2];   // (H,2H)
    const float* b_attn = (const float*)d_in[3];   // (H,)
    const float* v      = (const float*)d_in[4];   // (H,)
    float* out = (float*)d_out;                    // (B,1,T)

    char* base = (char*)d_ws;
    short* W2p = (short*)base;                          // 524288 B
    float* hb  = (float*)(base + 524288);               // 65536 B
    float* sp  = (float*)(base + 589824);               // 1048576 B
    short* Aimg = (short*)(base + 1638400);             // 67108864 B (new path)
    const size_t need = 1638400ull + 67108864ull;

    if (ws_size >= need) {
        prep_all_kernel<<<5184, 256, 0, stream>>>(W, hidden, b_attn, enc, W2p, hb, Aimg);
        attn_main_lds_kernel<<<2048, 256, 0, stream>>>(Aimg, W2p, hb, v, sp);
    } else {
        prep_kernel<<<1088, 256, 0, stream>>>(W, hidden, b_attn, W2p, hb);
        attn_main_kernel<<<2048, 256, 0, stream>>>(enc, W2p, hb, v, sp);
    }
    softmax_kernel<<<32, 256, 0, stream>>>(sp, out);
}

// Round 20
// 87.151 us; speedup vs baseline: 1.2366x; 1.2366x over previous
//
#include <hip/hip_runtime.h>
#include <hip/hip_bf16.h>

// Problem: T=2048, B=32, H=512
//   scores[b,t] = sum_o v[o] * tanh( hb[b,o] + sum_h enc[t,b,h] * W2[o,h] )
//   out[b,0,t]  = softmax_t(scores[b,:])
//
// R20 INSIGHT: enc (T,B,H) is a contiguous 65536x512 row-major matrix under
// r = t*32+b. All prior M-tiles used FIXED b -> 256B-per-64KB-stride reads
// (~25% DRAM efficiency, the session-long ~1 TB/s anchor). This round: M-tile
// = 128 CONTIGUOUS r-rows (one linear 256KB slab). Everything else = R16
// verified structure (dbuf LDS, B via gload_lds from pre-swizzled image,
// A dist-2 reg ping-pong, XCD remap, merged prep).
//
// HARD-WON RULES (R2..R19): WRITE>>2MB on MAIN = spill; gload_lds dest is
// wave-uniform+lane*16B (per-wave dests); occupancy not the lever; counted
// vmcnt/setprio negative on 2-phase; trivial conversion passes get VGPR-
// starved and latency-bound — avoid extra passes entirely.

#define TT 2048
#define BB 32
#define HH 512

typedef __attribute__((ext_vector_type(8))) short bf16x8;
typedef __attribute__((ext_vector_type(4))) float f32x4;

static __device__ __forceinline__ unsigned cvt2(float a, float b) {
    union { __hip_bfloat162 h; unsigned u; } cv;
    cv.h = __float22bfloat162_rn(make_float2(a, b));   // v_cvt_pk_bf16_f32
    return cv.u;
}

static __device__ __forceinline__ unsigned short f2bf(float f) {
    unsigned int u = __float_as_uint(f);
    unsigned int r = (u + 0x7FFFu + ((u >> 16) & 1u)) >> 16;  // RNE
    return (unsigned short)r;
}

// tanh(x) = 1 - 2/(1+e^{2x});  inf-safe at both ends.
static __device__ __forceinline__ float fast_tanh(float x) {
    float e = __expf(2.0f * x);
    return 1.0f - 2.0f * __builtin_amdgcn_rcpf(1.0f + e);
}

static __device__ __forceinline__ void gload_lds16(const void* g, void* l) {
    __builtin_amdgcn_global_load_lds(
        (const __attribute__((address_space(1))) unsigned int*)g,
        (__attribute__((address_space(3))) unsigned int*)l, 16, 0, 0);
}

// ---- Kernel 1 (merged prep, = R16): blocks [0,1024) pack W2 swizzled image;
// blocks [1024,1088) compute hb.
__global__ void prep_kernel(const float* __restrict__ W,
                            const float* __restrict__ hidden,
                            const float* __restrict__ b_attn,
                            short* __restrict__ W2p,
                            float* __restrict__ hb) {
    __shared__ float hrow[512];
    const int bid = blockIdx.x;
    if (bid < 1024) {
        int idx = bid * 256 + threadIdx.x;      // 262144 total
        int nt = idx >> 16;
        int ks = (idx >> 13) & 7;
        int s  = idx & 8191;
        int j  = s >> 6;
        int c  = s & 63;
        int o  = nt * 128 + j;
        int k  = ks * 64 + (c ^ ((j & 7) << 3));
        W2p[idx] = (short)f2bf(W[o * 1024 + 512 + k]);
    } else {
        const int hbid = bid - 1024;
        int b = hbid >> 1;
        int o = ((hbid & 1) << 8) + threadIdx.x;
        for (int h = threadIdx.x; h < 512; h += 256) hrow[h] = hidden[b * 512 + h];
        __syncthreads();
        const float4* wr = reinterpret_cast<const float4*>(W + (size_t)o * 1024);
        const float4* hr = reinterpret_cast<const float4*>(hrow);
        float acc = b_attn[o];
#pragma unroll 8
        for (int i = 0; i < 128; ++i) {
            float4 w = wr[i], h4 = hr[i];
            acc += w.x * h4.x + w.y * h4.y + w.z * h4.z + w.w * h4.w;
        }
        hb[b * 512 + o] = acc;
    }
}

// ---- Kernel 2: 128x128-tile double-buffered GEMM + fused tanh/v-dot epilogue.
// M-rows are CONTIGUOUS r = t*32+b. Grid 2048, XCD remap w=(bid&7)*256+(bid>>3);
// nt=w&3, mtile=w>>2, rows r0=mtile*128..+128 (one linear 256KB slab of enc).
// 256 threads = 4 waves (wr x wc = 2x2), wave tile 64x64. K=512 in 8 steps.
// A: dist-2 reg prefetch ping-pong -> cvt -> swizzled ds_write.
// B: global_load_lds from pre-swizzled W2p, 1-ahead, per-wave dests.
__global__ __launch_bounds__(256, 2) void attn_main_kernel(
    const float* __restrict__ enc, const short* __restrict__ W2p,
    const float* __restrict__ hb, const float* __restrict__ v,
    float* __restrict__ scores_part)
{
    __shared__ short As[2][128 * 64];   // swizzled: col c2 = c ^ ((r&7)<<3)
    __shared__ short Bs[2][128 * 64];   // image pre-swizzled by prep kernel
    __shared__ float s_red[2][128];

    const int tid = threadIdx.x;
    const int bid = blockIdx.x;
    const int w = (bid & 7) * 256 + (bid >> 3);  // XCD-contiguous (bijective)
    const int nt = w & 3;                // N-tile (128 o-cols)
    const int mtile = w >> 2;            // 512 M-tiles
    const int r0 = mtile * 128;          // contiguous global row base (r = t*32+b)

    const int wave = tid >> 6;
    const int lane = tid & 63;
    const int wr = wave >> 1;            // row half (64 rows)
    const int wc = wave & 1;             // col half (64 cols)
    const int lcol = lane & 15;
    const int lq = lane >> 4;

    // A staging: pass p: row r = p*32 + (tid>>3), float col (tid&7)*8
    const int arow = tid >> 3;           // 0..31
    const int afc = (tid & 7) * 8;       // 0..56
    const float* encbase = enc + (size_t)(r0 + arow) * HH + afc;
    // B staging source (shorts): + ks*8192 per step; lane offset baked in
    const short* bsrc = W2p + nt * 65536 + (wave * 4) * 512 + lane * 8;

    f32x4 acc[4][4];
#pragma unroll
    for (int mt = 0; mt < 4; ++mt)
#pragma unroll
        for (int ns = 0; ns < 4; ++ns) acc[mt][ns] = (f32x4){0.f, 0.f, 0.f, 0.f};

    float4 rA0[8], rA1[8];

#define A_LOAD(RA, KS)                                                              \
    {                                                                               \
        _Pragma("unroll")                                                           \
        for (int p = 0; p < 4; ++p) {                                               \
            const float* src = encbase + (size_t)p * 32 * HH + (KS) * 64;           \
            RA[p * 2]     = *reinterpret_cast<const float4*>(src);                  \
            RA[p * 2 + 1] = *reinterpret_cast<const float4*>(src + 4);              \
        }                                                                           \
    }

#define B_STAGE(KS, BUF)                                                            \
    {                                                                               \
        const short* s0 = bsrc + (KS) * 8192;                                       \
        _Pragma("unroll")                                                           \
        for (int c = 0; c < 4; ++c)                                                 \
            gload_lds16(s0 + c * 512, &Bs[BUF][(wave * 4 + c) * 512]);              \
    }

#define A_WRITE(RA, BUF)                                                            \
    {                                                                               \
        _Pragma("unroll")                                                           \
        for (int p = 0; p < 4; ++p) {                                               \
            const int r = p * 32 + arow;                                            \
            uint4 pk;                                                               \
            pk.x = cvt2(RA[p * 2].x, RA[p * 2].y);                                  \
            pk.y = cvt2(RA[p * 2].z, RA[p * 2].w);                                  \
            pk.z = cvt2(RA[p * 2 + 1].x, RA[p * 2 + 1].y);                          \
            pk.w = cvt2(RA[p * 2 + 1].z, RA[p * 2 + 1].w);                          \
            const int cs = afc ^ ((r & 7) << 3);                                    \
            *reinterpret_cast<uint4*>(&As[BUF][r * 64 + cs]) = pk;                  \
        }                                                                           \
    }

#define COMPUTE(BUF)                                                                \
    {                                                                               \
        _Pragma("unroll")                                                           \
        for (int ksub = 0; ksub < 2; ++ksub) {                                      \
            const int kk = ksub * 32 + lq * 8;                                      \
            bf16x8 af[4], bfr[4];                                                   \
            _Pragma("unroll")                                                       \
            for (int mt = 0; mt < 4; ++mt) {                                        \
                const int r = wr * 64 + mt * 16 + lcol;                             \
                af[mt] = *reinterpret_cast<const bf16x8*>(                          \
                    &As[BUF][r * 64 + (kk ^ ((r & 7) << 3))]);                      \
            }                                                                       \
            _Pragma("unroll")                                                       \
            for (int ns = 0; ns < 4; ++ns) {                                        \
                const int j = wc * 64 + ns * 16 + lcol;                             \
                bfr[ns] = *reinterpret_cast<const bf16x8*>(                         \
                    &Bs[BUF][j * 64 + (kk ^ ((j & 7) << 3))]);                      \
            }                                                                       \
            _Pragma("unroll")                                                       \
            for (int mt = 0; mt < 4; ++mt)                                          \
                _Pragma("unroll")                                                   \
                for (int ns = 0; ns < 4; ++ns)                                      \
                    acc[mt][ns] = __builtin_amdgcn_mfma_f32_16x16x32_bf16(          \
                        af[mt], bfr[ns], acc[mt][ns], 0, 0, 0);                     \
        }                                                                           \
    }

    // ---- prologue: stage step 0; preload step 1 into rA1
    A_LOAD(rA0, 0);
    A_LOAD(rA1, 1);
    B_STAGE(0, 0);
    A_WRITE(rA0, 0);
    __syncthreads();

    // ---- main K-loop: 8 steps, hand-unrolled x2, static ping-pong.
#pragma unroll
    for (int s2 = 0; s2 < 4; ++s2) {
        const int s = s2 * 2;
        if (s + 2 < 8) A_LOAD(rA0, s + 2);
        B_STAGE(s + 1, 1);
        COMPUTE(0);
        A_WRITE(rA1, 1);
        __syncthreads();
        if (s + 3 < 8) A_LOAD(rA1, s + 3);
        if (s + 2 < 8) B_STAGE(s + 2, 0);
        COMPUTE(1);
        if (s + 2 < 8) {
            A_WRITE(rA0, 0);
            __syncthreads();
        }
    }

    // ---- epilogue: tanh + v-dot; hb depends on b = (local row)&31 per row.
    // acc[mt][ns][j] is local row wr*64 + mt*16 + lq*4 + j, col wc*64+ns*16+lcol.
    float part[4][4];
#pragma unroll
    for (int mt = 0; mt < 4; ++mt)
#pragma unroll
        for (int j = 0; j < 4; ++j) part[mt][j] = 0.0f;

#pragma unroll
    for (int ns = 0; ns < 4; ++ns) {
        const int o = nt * 128 + wc * 64 + ns * 16 + lcol;
        const float vv = v[o];
        const float* hbcol = hb + o;
#pragma unroll
        for (int mt = 0; mt < 4; ++mt) {
            const int bbase = (mt * 16 + lq * 4) & 31;   // wr*64 ≡ 0 (mod 32)
#pragma unroll
            for (int j = 0; j < 4; ++j) {
                const float hbv = hbcol[(bbase + j) * 512];
                const float x = acc[mt][ns][j] + hbv;
                part[mt][j] = fmaf(fast_tanh(x), vv, part[mt][j]);
            }
        }
    }

#pragma unroll
    for (int off = 1; off < 16; off <<= 1)
#pragma unroll
        for (int mt = 0; mt < 4; ++mt)
#pragma unroll
            for (int j = 0; j < 4; ++j)
                part[mt][j] += __shfl_xor(part[mt][j], off, 64);

    if (lcol == 0) {
#pragma unroll
        for (int mt = 0; mt < 4; ++mt)
#pragma unroll
            for (int j = 0; j < 4; ++j)
                s_red[wc][wr * 64 + mt * 16 + lq * 4 + j] = part[mt][j];
    }
    __syncthreads();

    // scores_part stored in r-order: sp[nt*65536 + r]
    if (tid < 128)
        scores_part[(size_t)nt * (TT * BB) + r0 + tid] =
            s_red[0][tid] + s_red[1][tid];
}

// ---- Kernel 3: sum 4 N-tile partials + softmax over T per b.
// sp is r-ordered (r = t*32+b): read sp[nt*65536 + t*32 + b].
__global__ void softmax_kernel(const float* __restrict__ sp, float* __restrict__ out) {
    __shared__ float wred[4];
    __shared__ float wsum[4];
    const int b = blockIdx.x;
    const int tid = threadIdx.x;   // 256
    float vals[8];
    float mx = -1e30f;
#pragma unroll
    for (int i = 0; i < 8; ++i) {
        const int t = i * 256 + tid;
        const size_t r = (size_t)t * BB + b;
        const float s = sp[r] + sp[(size_t)(TT * BB) + r] +
                        sp[(size_t)2 * (TT * BB) + r] + sp[(size_t)3 * (TT * BB) + r];
        vals[i] = s;
        mx = fmaxf(mx, s);
    }
#pragma unroll
    for (int off = 32; off; off >>= 1) mx = fmaxf(mx, __shfl_xor(mx, off, 64));
    if ((tid & 63) == 0) wred[tid >> 6] = mx;
    __syncthreads();
    mx = fmaxf(fmaxf(wred[0], wred[1]), fmaxf(wred[2], wred[3]));
    float s = 0.0f;
#pragma unroll
    for (int i = 0; i < 8; ++i) {
        vals[i] = __expf(vals[i] - mx);
        s += vals[i];
    }
#pragma unroll
    for (int off = 32; off; off >>= 1) s += __shfl_xor(s, off, 64);
    if ((tid & 63) == 0) wsum[tid >> 6] = s;
    __syncthreads();
    s = wsum[0] + wsum[1] + wsum[2] + wsum[3];
    const float inv = 1.0f / s;
#pragma unroll
    for (int i = 0; i < 8; ++i) out[b * TT + i * 256 + tid] = vals[i] * inv;
}

extern "C" void kernel_launch(void* const* d_in, const int* in_sizes, int n_in,
                              void* d_out, int out_size, void* d_ws, size_t ws_size,
                              hipStream_t stream) {
    const float* hidden = (const float*)d_in[0];   // (1,B,H)
    const float* enc    = (const float*)d_in[1];   // (T,B,H)
    const float* W      = (const float*)d_in[2];   // (H,2H)
    const float* b_attn = (const float*)d_in[3];   // (H,)
    const float* v      = (const float*)d_in[4];   // (H,)
    float* out = (float*)d_out;                    // (B,1,T)

    char* base = (char*)d_ws;
    short* W2p = (short*)base;                          // 524288 B
    float* hb  = (float*)(base + 524288);               // 65536 B
    float* sp  = (float*)(base + 589824);               // 4*65536*4 = 1048576 B

    prep_kernel<<<1088, 256, 0, stream>>>(W, hidden, b_attn, W2p, hb);
    attn_main_kernel<<<2048, 256, 0, stream>>>(enc, W2p, hb, v, sp);
    softmax_kernel<<<32, 256, 0, stream>>>(sp, out);
}